// Round 4
// baseline (229.461 us; speedup 1.0000x reference)
//
#include <hip/hip_runtime.h>

#define B_N 65536
#define K_SCALE 2.885390081777927f   // 2*log2(e): folded into W1-family & W2 weights

typedef __attribute__((ext_vector_type(8))) __bf16 bf16x8;
typedef __attribute__((ext_vector_type(4))) float f32x4;
typedef __attribute__((ext_vector_type(4))) unsigned int uint32x4;

// acc already holds 2*log2e*x: tanh(x) = 1 - 2/(2^acc + 1). Saturates cleanly.
__device__ __forceinline__ float tanh_scaled(float a) {
    float e;
    asm("v_exp_f32 %0, %1" : "=v"(e) : "v"(a));
    return fmaf(-2.0f, __builtin_amdgcn_rcpf(e + 1.0f), 1.0f);
}

__device__ __forceinline__ unsigned cvt_pk_bf16(float lo, float hi) {
    unsigned r;
    asm("v_cvt_pk_bf16_f32 %0, %1, %2" : "=v"(r) : "v"(lo), "v"(hi));
    return r;
}

// K-index bit permutation: [kt][q:2][j2:1][j:2] -> [kt][j2:1][q:2][j:2].
// Baking sigma into the consumer weight's K order makes the producer MFMA's
// C-layout output (lane-local, col = lane&15 = own batch row) coincide
// EXACTLY with the consumer MFMA's B-fragment register layout.
__device__ __forceinline__ int sigma(int m) {
    return (m & 96) | ((m & 4) << 2) | ((m >> 1) & 12) | (m & 3);
}

// ---------- single fused kernel ----------
// 1 wave/SIMD, full 512-reg file: ALL weights in registers, step loop has zero
// memory ops. Each wave runs TWO independent 16-row streams in the same loop
// body (latency hiding). Each block self-computes max|td| and its own weight
// fragments from an f32 LDS stage (LDS dead after prologue, one barrier).
// grid = 256 = 1 block/CU; 4 waves/block; 2 pairs x 2 streams x 16 rows x ...
__launch_bounds__(256, 1)
__global__ void k_all(const float* __restrict__ z_in, const float* __restrict__ td,
                      const float* __restrict__ W1, const float* __restrict__ b1,
                      const float* __restrict__ W2, const float* __restrict__ b2,
                      const float* __restrict__ W3, const float* __restrict__ b3,
                      float* __restrict__ out) {
    __shared__ float w1s[65 * 128];    // 33280 B
    __shared__ float w2s[128 * 128];   // 65536 B
    __shared__ float w3s[128 * 64];    // 32768 B
    __shared__ float red[4];

    const int tid = threadIdx.x;
    const int wave = tid >> 6, lane = tid & 63;
    const int q = lane >> 4, m15 = lane & 15;

    // ---- block-local max|td| (td is L2/L3-hot after first block touches) ----
    float mx = 0.0f;
    const f32x4* tdv = (const f32x4*)td;
    for (int c = tid; c < B_N / 4; c += 256) {
        f32x4 v = tdv[c];
        mx = fmaxf(mx, fmaxf(fmaxf(fabsf(v[0]), fabsf(v[1])),
                             fmaxf(fabsf(v[2]), fabsf(v[3]))));
    }
#pragma unroll
    for (int o = 32; o; o >>= 1) mx = fmaxf(mx, __shfl_down(mx, o));
    if (lane == 0) red[wave] = mx;

    // ---- stage raw f32 weights into LDS (coalesced float4) ----
    for (int c = tid; c < 2080; c += 256) ((f32x4*)w1s)[c] = ((const f32x4*)W1)[c];
    for (int c = tid; c < 4096; c += 256) ((f32x4*)w2s)[c] = ((const f32x4*)W2)[c];
    for (int c = tid; c < 2048; c += 256) ((f32x4*)w3s)[c] = ((const f32x4*)W3)[c];
    __syncthreads();   // the only barrier

    const float maxab = fmaxf(fmaxf(red[0], red[1]), fmaxf(red[2], red[3]));
    const int steps = (int)ceil((double)maxab / 0.1);   // matches np.ceil(float64)

    // ---- gather sigma-permuted, scaled bf16 fragments into registers ----
    const int col128 = m15;   // column within fragment
    auto mkfrag = [&](const float* base, int ldn, int col, int mbase,
                      float scale) -> bf16x8 {
        unsigned w[4];
#pragma unroll
        for (int jp = 0; jp < 4; ++jp) {
            float lo = base[sigma(mbase + 2 * jp) * ldn + col] * scale;
            float hi = base[sigma(mbase + 2 * jp + 1) * ldn + col] * scale;
            w[jp] = cvt_pk_bf16(lo, hi);
        }
        return __builtin_bit_cast(bf16x8, (uint32x4){w[0], w[1], w[2], w[3]});
    };

    bf16x8 wzf[8][2];   //  64 regs: Wz A-fragments (scaled)
    bf16x8 w2f[8][4];   // 128 regs: W2 A-fragments (scaled)
    bf16x8 w3f[4][4];   //  64 regs: W3 A-fragments (unscaled)
    bf16x8 augf[8];     //  32 regs: {pack(K*Wt, K*b1),0,0,0} on q==0 lanes
#pragma unroll
    for (int n0 = 0; n0 < 8; ++n0)
#pragma unroll
        for (int kt = 0; kt < 2; ++kt)
            wzf[n0][kt] = mkfrag(w1s, 128, n0 * 16 + col128, kt * 32 + q * 8, K_SCALE);
#pragma unroll
    for (int n0 = 0; n0 < 8; ++n0)
#pragma unroll
        for (int kt = 0; kt < 4; ++kt)
            w2f[n0][kt] = mkfrag(w2s, 128, n0 * 16 + col128, kt * 32 + q * 8, K_SCALE);
#pragma unroll
    for (int n0 = 0; n0 < 4; ++n0)
#pragma unroll
        for (int kt = 0; kt < 4; ++kt)
            w3f[n0][kt] = mkfrag(w3s, 64, n0 * 16 + col128, kt * 32 + q * 8, 1.0f);
#pragma unroll
    for (int n0 = 0; n0 < 8; ++n0) {
        const int n = n0 * 16 + m15;
        unsigned w = cvt_pk_bf16(w1s[64 * 128 + n] * K_SCALE, b1[n] * K_SCALE);
        w = (q == 0) ? w : 0u;   // only k-slots 64,65 are live
        augf[n0] = __builtin_bit_cast(bf16x8, (uint32x4){w, 0u, 0u, 0u});
    }

    // b2 (scaled) rides in as the C-init of the first L2 MFMA
    f32x4 b2c[8];
#pragma unroll
    for (int n0 = 0; n0 < 8; ++n0) {
        f32x4 v = *(const f32x4*)&b2[n0 * 16 + q * 4];
#pragma unroll
        for (int r = 0; r < 4; ++r) v[r] *= K_SCALE;
        b2c[n0] = v;
    }

    // ---- main loop: 2 pairs of 2 interleaved independent streams ----
    for (int p = 0; p < 2; ++p) {
        const int row0 = blockIdx.x * 256 + (2 * p) * 64 + wave * 16 + m15;

        float zr[2][16];
        float dtr[2], tdr[2];
#pragma unroll
        for (int u = 0; u < 2; ++u) {
            const int row = row0 + u * 64;
#pragma unroll
            for (int kt = 0; kt < 2; ++kt)
#pragma unroll
                for (int hi = 0; hi < 2; ++hi) {
                    f32x4 v = *(const f32x4*)(z_in + (size_t)row * 64 + kt * 32 + hi * 16 + q * 4);
#pragma unroll
                    for (int r = 0; r < 4; ++r) zr[u][kt * 8 + hi * 4 + r] = v[r];
                }
            tdr[u] = td[row];
            dtr[u] = (steps > 0) ? (tdr[u] / (float)steps) : 0.0f;
        }

        for (int s = 0; s < steps; ++s) {
            const float tt = (float)s * 0.1f;
            unsigned tws = cvt_pk_bf16(tt, 1.0f);
            tws = (q == 0) ? tws : 0u;
            const bf16x8 zA2 = __builtin_bit_cast(bf16x8, (uint32x4){tws, 0u, 0u, 0u});

            // ---- layer 1 (both streams): pre1 = K*(z@Wz + t*Wt + b1) ----
            unsigned hv[2][16];
#pragma unroll
            for (int u = 0; u < 2; ++u) {
                unsigned za[8];
#pragma unroll
                for (int i = 0; i < 8; ++i)
                    za[i] = cvt_pk_bf16(zr[u][2 * i], zr[u][2 * i + 1]);
                const bf16x8 zA0 = __builtin_bit_cast(bf16x8, (uint32x4){za[0], za[1], za[2], za[3]});
                const bf16x8 zA1 = __builtin_bit_cast(bf16x8, (uint32x4){za[4], za[5], za[6], za[7]});
#pragma unroll
                for (int n0 = 0; n0 < 8; ++n0) {
                    f32x4 acc = {0.f, 0.f, 0.f, 0.f};
                    acc = __builtin_amdgcn_mfma_f32_16x16x32_bf16(wzf[n0][0], zA0, acc, 0, 0, 0);
                    acc = __builtin_amdgcn_mfma_f32_16x16x32_bf16(wzf[n0][1], zA1, acc, 0, 0, 0);
                    acc = __builtin_amdgcn_mfma_f32_16x16x32_bf16(augf[n0],   zA2, acc, 0, 0, 0);
                    hv[u][n0 * 2 + 0] = cvt_pk_bf16(tanh_scaled(acc[0]), tanh_scaled(acc[1]));
                    hv[u][n0 * 2 + 1] = cvt_pk_bf16(tanh_scaled(acc[2]), tanh_scaled(acc[3]));
                }
            }

            // ---- layer 2 (both streams): pre2 = K*(h1@W2 + b2) ----
            unsigned gv[2][16];
#pragma unroll
            for (int u = 0; u < 2; ++u)
#pragma unroll
                for (int n0 = 0; n0 < 8; ++n0) {
                    f32x4 acc = b2c[n0];
#pragma unroll
                    for (int kt = 0; kt < 4; ++kt) {
                        const bf16x8 hf = __builtin_bit_cast(
                            bf16x8, (uint32x4){hv[u][4 * kt], hv[u][4 * kt + 1],
                                               hv[u][4 * kt + 2], hv[u][4 * kt + 3]});
                        acc = __builtin_amdgcn_mfma_f32_16x16x32_bf16(w2f[n0][kt], hf, acc, 0, 0, 0);
                    }
                    gv[u][n0 * 2 + 0] = cvt_pk_bf16(tanh_scaled(acc[0]), tanh_scaled(acc[1]));
                    gv[u][n0 * 2 + 1] = cvt_pk_bf16(tanh_scaled(acc[2]), tanh_scaled(acc[3]));
                }

            // ---- layer 3 (both streams): dz = h2@W3; z += dz*dt (f32) ----
#pragma unroll
            for (int u = 0; u < 2; ++u)
#pragma unroll
                for (int n0 = 0; n0 < 4; ++n0) {
                    f32x4 acc = {0.f, 0.f, 0.f, 0.f};
#pragma unroll
                    for (int kt = 0; kt < 4; ++kt) {
                        const bf16x8 gf = __builtin_bit_cast(
                            bf16x8, (uint32x4){gv[u][4 * kt], gv[u][4 * kt + 1],
                                               gv[u][4 * kt + 2], gv[u][4 * kt + 3]});
                        acc = __builtin_amdgcn_mfma_f32_16x16x32_bf16(w3f[n0][kt], gf, acc, 0, 0, 0);
                    }
#pragma unroll
                    for (int r = 0; r < 4; ++r)
                        zr[u][n0 * 4 + r] = fmaf(acc[r], dtr[u], zr[u][n0 * 4 + r]);
                }
        }

        // ---- epilogue: b3 fold (sum_s dtr*b3 == td*b3, exact) + store ----
#pragma unroll
        for (int u = 0; u < 2; ++u) {
            const int row = row0 + u * 64;
            const float tb3 = (steps > 0) ? tdr[u] : 0.0f;
#pragma unroll
            for (int n0 = 0; n0 < 4; ++n0) {
                f32x4 bb = *(const f32x4*)&b3[n0 * 16 + q * 4];
#pragma unroll
                for (int r = 0; r < 4; ++r)
                    zr[u][n0 * 4 + r] = fmaf(tb3, bb[r], zr[u][n0 * 4 + r]);
            }
#pragma unroll
            for (int kt = 0; kt < 2; ++kt)
#pragma unroll
                for (int hi = 0; hi < 2; ++hi) {
                    f32x4 v;
#pragma unroll
                    for (int r = 0; r < 4; ++r) v[r] = zr[u][kt * 8 + hi * 4 + r];
                    *(f32x4*)(out + (size_t)row * 64 + kt * 32 + hi * 16 + q * 4) = v;
                }
        }
    }
}

extern "C" void kernel_launch(void* const* d_in, const int* in_sizes, int n_in,
                              void* d_out, int out_size, void* d_ws, size_t ws_size,
                              hipStream_t stream) {
    const float* z  = (const float*)d_in[0];
    const float* td = (const float*)d_in[1];
    const float* W1 = (const float*)d_in[2];
    const float* b1 = (const float*)d_in[3];
    const float* W2 = (const float*)d_in[4];
    const float* b2 = (const float*)d_in[5];
    const float* W3 = (const float*)d_in[6];
    const float* b3 = (const float*)d_in[7];
    float* out = (float*)d_out;
    (void)in_sizes; (void)n_in; (void)out_size; (void)d_ws; (void)ws_size;

    k_all<<<256, 256, 0, stream>>>(z, td, W1, b1, W2, b2, W3, b3, out);
}

// Round 10
// 208.775 us; speedup vs baseline: 1.0991x; 1.0991x over previous
//
#include <hip/hip_runtime.h>

#define B_N 65536
#define K_SCALE 2.885390081777927f   // 2*log2(e): folded into W1-family & W2 weights

typedef __attribute__((ext_vector_type(8))) __bf16 bf16x8;
typedef __attribute__((ext_vector_type(8))) unsigned short ushort8;
typedef __attribute__((ext_vector_type(4))) float f32x4;
typedef __attribute__((ext_vector_type(4))) unsigned int uint32x4;

// ---------- ws layout (bytes) ----------
// 0     : unsigned max|time_delta| bits (atomicMax target; memset to 0 first)
// 64    : WzT  bf16 [128][64]   sigma-z-permuted K, scaled by K_SCALE
// 16448 : W2T  bf16 [128][128]  sigma-permuted K,   scaled by K_SCALE
// 49216 : W3T  bf16 [64][128]   sigma-permuted K,   UNSCALED

__device__ __forceinline__ unsigned short f2bf(float f) {
    unsigned u = __float_as_uint(f);
    u += 0x7FFFu + ((u >> 16) & 1u);   // RNE
    return (unsigned short)(u >> 16);
}

// acc already holds 2*log2e*x: tanh(x) = 1 - 2/(2^acc + 1). Saturates cleanly.
__device__ __forceinline__ float tanh_scaled(float a) {
    float e;
    asm("v_exp_f32 %0, %1" : "=v"(e) : "v"(a));
    return fmaf(-2.0f, __builtin_amdgcn_rcpf(e + 1.0f), 1.0f);
}

__device__ __forceinline__ unsigned cvt_pk_bf16(float lo, float hi) {
    unsigned r;
    asm("v_cvt_pk_bf16_f32 %0, %1, %2" : "=v"(r) : "v"(lo), "v"(hi));
    return r;
}

// K-index bit permutation: [kt][q:2][j2:1][j:2] -> [kt][j2:1][q:2][j:2].
// Baking sigma into the consumer weight's K order makes the producer MFMA's
// C-layout output (lane-local, col = lane&15 = own batch row) coincide
// EXACTLY with the consumer MFMA's B-fragment register layout.
__device__ __forceinline__ int sigma(int m) {
    return (m & 96) | ((m & 4) << 2) | ((m >> 1) & 12) | (m & 3);
}

// ---------- kernel 1: max|td| reduce (blocks 0..63) + weight prep (64..191) --
__global__ void k_pre(const float* __restrict__ td, const float* __restrict__ W1,
                      const float* __restrict__ W2, const float* __restrict__ W3,
                      unsigned* __restrict__ ws) {
    if (blockIdx.x < 64) {
        int i = blockIdx.x * blockDim.x + threadIdx.x;
        float m = 0.0f;
        for (; i < B_N; i += 64 * 256) m = fmaxf(m, fabsf(td[i]));
#pragma unroll
        for (int o = 32; o; o >>= 1) m = fmaxf(m, __shfl_down(m, o));
        if ((threadIdx.x & 63) == 0) atomicMax(ws, __float_as_uint(m));
    } else {
        // 128 blocks * 256 threads = 32768 = exactly one bf16 element each
        int i = (blockIdx.x - 64) * 256 + threadIdx.x;
        unsigned short* wsb = (unsigned short*)(ws + 16);   // ws + 64 bytes
        float v;
        if (i < 8192) {                    // WzT[n][m] = K*W1[sigma(m)][n]
            int n = i >> 6, m = i & 63;
            v = W1[sigma(m) * 128 + n] * K_SCALE;
        } else if (i < 24576) {            // W2T[n][m] = K*W2[sigma(m)][n]
            int o = i - 8192;
            int n = o >> 7, m = o & 127;
            v = W2[sigma(m) * 128 + n] * K_SCALE;
        } else {                           // W3T[n][m] = W3[sigma(m)][n] (unscaled)
            int o = i - 24576;
            int n = o >> 7, m = o & 127;
            v = W3[sigma(m) * 64 + n];
        }
        wsb[i] = f2bf(v);
    }
}

// ---------- kernel 2: the ODE solver ----------
// 1 wave/SIMD (full 512-reg file per wave): ALL weights live in registers,
// the step loop has ZERO memory operations (no LDS, no global, no barriers).
// block = 256 = 4 waves (one per SIMD); grid = 256 = 1 block/CU;
// each wave runs 4 sequential 64-row tiles (prologue paid once).
__launch_bounds__(256, 1)
__global__ void k_main(const float* __restrict__ z_in, const float* __restrict__ td,
                       const float* __restrict__ W1, const float* __restrict__ b1,
                       const float* __restrict__ b2, const float* __restrict__ b3,
                       const void* __restrict__ ws, float* __restrict__ out) {
    const unsigned* wsu = (const unsigned*)ws;
    const unsigned short* wzg = (const unsigned short*)((const char*)ws + 64);
    const unsigned short* w2g = wzg + 8192;
    const unsigned short* w3g = wzg + 24576;

    const int tid = threadIdx.x;
    const int wave = tid >> 6;
    const int lane = tid & 63;
    const int q = lane >> 4;
    const int m15 = lane & 15;

    // ---- hoist ALL loop-invariant weights into registers ----
    bf16x8 wzf[8][2];   //  64 regs: Wz A-fragments (scaled)
    bf16x8 w2f[8][4];   // 128 regs: W2 A-fragments (scaled)
    bf16x8 w3f[4][4];   //  64 regs: W3 A-fragments (unscaled)
    bf16x8 augf[8];     //  32 regs: aug A-frag {pack(K*Wt, K*b1),0,0,0} on q==0
#pragma unroll
    for (int n0 = 0; n0 < 8; ++n0)
#pragma unroll
        for (int kt = 0; kt < 2; ++kt)
            wzf[n0][kt] = __builtin_bit_cast(
                bf16x8, *(const ushort8*)&wzg[(n0 * 16 + m15) * 64 + kt * 32 + q * 8]);
#pragma unroll
    for (int n0 = 0; n0 < 8; ++n0)
#pragma unroll
        for (int kt = 0; kt < 4; ++kt)
            w2f[n0][kt] = __builtin_bit_cast(
                bf16x8, *(const ushort8*)&w2g[(n0 * 16 + m15) * 128 + kt * 32 + q * 8]);
#pragma unroll
    for (int n0 = 0; n0 < 4; ++n0)
#pragma unroll
        for (int kt = 0; kt < 4; ++kt)
            w3f[n0][kt] = __builtin_bit_cast(
                bf16x8, *(const ushort8*)&w3g[(n0 * 16 + m15) * 128 + kt * 32 + q * 8]);
#pragma unroll
    for (int n0 = 0; n0 < 8; ++n0) {
        const int n = n0 * 16 + m15;
        float wt = W1[64 * 128 + n] * K_SCALE;   // Wt row of W1, scaled
        float bb = b1[n] * K_SCALE;
        unsigned w = (unsigned)f2bf(wt) | ((unsigned)f2bf(bb) << 16);
        w = (q == 0) ? w : 0u;                   // only k-slots 64,65 are live
        augf[n0] = __builtin_bit_cast(bf16x8, (uint32x4){w, 0u, 0u, 0u});
    }

    // b2 (scaled) rides in as the C-init of the first L2 MFMA
    f32x4 b2c[8];
#pragma unroll
    for (int n0 = 0; n0 < 8; ++n0) {
        f32x4 v = *(const f32x4*)&b2[n0 * 16 + q * 4];
#pragma unroll
        for (int r = 0; r < 4; ++r) v[r] *= K_SCALE;
        b2c[n0] = v;
    }

    const float maxab = __uint_as_float(wsu[0]);
    const int steps = (int)ceil((double)maxab / 0.1);   // matches np.ceil(float64)

    for (int tile = 0; tile < 4; ++tile) {
        const int row = blockIdx.x * 256 + tile * 64 + wave * 16 + m15;

        // zr[kt*8+hi*4+r] = z[row][kt*32 + hi*16 + q*4 + r]  (sigma_z baked in Wz)
        float zr[16];
#pragma unroll
        for (int kt = 0; kt < 2; ++kt)
#pragma unroll
            for (int hi = 0; hi < 2; ++hi) {
                f32x4 v = *(const f32x4*)(z_in + (size_t)row * 64 + kt * 32 + hi * 16 + q * 4);
#pragma unroll
                for (int r = 0; r < 4; ++r) zr[kt * 8 + hi * 4 + r] = v[r];
            }
        const float tdr = td[row];
        const float dtr = (steps > 0) ? (tdr / (float)steps) : 0.0f;

        for (int s = 0; s < steps; ++s) {
            const float t = (float)s * 0.1f;

            // ---- z -> bf16 B-fragments (8 cvt_pk) + t-augmentation word ----
            unsigned za[8];
#pragma unroll
            for (int i = 0; i < 8; ++i) za[i] = cvt_pk_bf16(zr[2 * i], zr[2 * i + 1]);
            unsigned tw = cvt_pk_bf16(t, 1.0f);
            tw = (q == 0) ? tw : 0u;
            bf16x8 zA0 = __builtin_bit_cast(bf16x8, (uint32x4){za[0], za[1], za[2], za[3]});
            bf16x8 zA1 = __builtin_bit_cast(bf16x8, (uint32x4){za[4], za[5], za[6], za[7]});
            bf16x8 zA2 = __builtin_bit_cast(bf16x8, (uint32x4){tw, 0u, 0u, 0u});

            // ---- layer 1: pre1 = K*(z@Wz + t*Wt + b1); h1 = tanh_scaled ----
            unsigned hv[16];
#pragma unroll
            for (int n0 = 0; n0 < 8; ++n0) {
                f32x4 acc = {0.f, 0.f, 0.f, 0.f};
                acc = __builtin_amdgcn_mfma_f32_16x16x32_bf16(wzf[n0][0], zA0, acc, 0, 0, 0);
                acc = __builtin_amdgcn_mfma_f32_16x16x32_bf16(wzf[n0][1], zA1, acc, 0, 0, 0);
                acc = __builtin_amdgcn_mfma_f32_16x16x32_bf16(augf[n0],   zA2, acc, 0, 0, 0);
                hv[n0 * 2 + 0] = cvt_pk_bf16(tanh_scaled(acc[0]), tanh_scaled(acc[1]));
                hv[n0 * 2 + 1] = cvt_pk_bf16(tanh_scaled(acc[2]), tanh_scaled(acc[3]));
            }

            // ---- layer 2: pre2 = K*(h1@W2 + b2) via scaled W2 + b2c C-init ----
            unsigned gv[16];
#pragma unroll
            for (int n0 = 0; n0 < 8; ++n0) {
                f32x4 acc = b2c[n0];
#pragma unroll
                for (int kt = 0; kt < 4; ++kt) {
                    bf16x8 hf = __builtin_bit_cast(
                        bf16x8, (uint32x4){hv[4 * kt], hv[4 * kt + 1],
                                           hv[4 * kt + 2], hv[4 * kt + 3]});
                    acc = __builtin_amdgcn_mfma_f32_16x16x32_bf16(w2f[n0][kt], hf, acc, 0, 0, 0);
                }
                gv[n0 * 2 + 0] = cvt_pk_bf16(tanh_scaled(acc[0]), tanh_scaled(acc[1]));
                gv[n0 * 2 + 1] = cvt_pk_bf16(tanh_scaled(acc[2]), tanh_scaled(acc[3]));
            }

            // ---- layer 3: dz = h2@W3 (unscaled); acc lands on zr[n0*4+r] ----
#pragma unroll
            for (int n0 = 0; n0 < 4; ++n0) {
                f32x4 acc = {0.f, 0.f, 0.f, 0.f};
#pragma unroll
                for (int kt = 0; kt < 4; ++kt) {
                    bf16x8 gf = __builtin_bit_cast(
                        bf16x8, (uint32x4){gv[4 * kt], gv[4 * kt + 1],
                                           gv[4 * kt + 2], gv[4 * kt + 3]});
                    acc = __builtin_amdgcn_mfma_f32_16x16x32_bf16(w3f[n0][kt], gf, acc, 0, 0, 0);
                }
#pragma unroll
                for (int r = 0; r < 4; ++r)
                    zr[n0 * 4 + r] = fmaf(acc[r], dtr, zr[n0 * 4 + r]);
            }
        }

        // b3 fold: sum_s dtr*b3 == td*b3 (exact linear fold, dz kept f32)
        const float tb3 = (steps > 0) ? tdr : 0.0f;
#pragma unroll
        for (int n0 = 0; n0 < 4; ++n0) {
            f32x4 bb = *(const f32x4*)&b3[n0 * 16 + q * 4];
#pragma unroll
            for (int r = 0; r < 4; ++r)
                zr[n0 * 4 + r] = fmaf(tb3, bb[r], zr[n0 * 4 + r]);
        }

        // store final z
#pragma unroll
        for (int kt = 0; kt < 2; ++kt)
#pragma unroll
            for (int hi = 0; hi < 2; ++hi) {
                f32x4 v;
#pragma unroll
                for (int r = 0; r < 4; ++r) v[r] = zr[kt * 8 + hi * 4 + r];
                *(f32x4*)(out + (size_t)row * 64 + kt * 32 + hi * 16 + q * 4) = v;
            }
    }
}

extern "C" void kernel_launch(void* const* d_in, const int* in_sizes, int n_in,
                              void* d_out, int out_size, void* d_ws, size_t ws_size,
                              hipStream_t stream) {
    const float* z  = (const float*)d_in[0];
    const float* td = (const float*)d_in[1];
    const float* W1 = (const float*)d_in[2];
    const float* b1 = (const float*)d_in[3];
    const float* W2 = (const float*)d_in[4];
    const float* b2 = (const float*)d_in[5];
    const float* W3 = (const float*)d_in[6];
    const float* b3 = (const float*)d_in[7];
    float* out = (float*)d_out;
    (void)in_sizes; (void)n_in; (void)out_size; (void)ws_size;

    hipMemsetAsync(d_ws, 0, 64, stream);
    k_pre<<<192, 256, 0, stream>>>(td, W1, W2, W3, (unsigned*)d_ws);
    k_main<<<256, 256, 0, stream>>>(z, td, W1, b1, b2, b3, d_ws, out);
}

// Round 11
// 205.753 us; speedup vs baseline: 1.1152x; 1.0147x over previous
//
#include <hip/hip_runtime.h>

#define B_N 65536
#define K_SCALE 2.885390081777927f   // 2*log2(e): folded into W1-family & W2 weights

typedef __attribute__((ext_vector_type(8))) __bf16 bf16x8;
typedef __attribute__((ext_vector_type(8))) unsigned short ushort8;
typedef __attribute__((ext_vector_type(4))) float f32x4;
typedef __attribute__((ext_vector_type(4))) unsigned int uint32x4;

// ---------- ws layout (bytes) ----------
// 0..255  : 64 f32 per-block partial max|td| (plain stores; NO memset needed —
//           every slot is written by k_pre before k_main reads it)
// 256     : WzT  bf16 [128][64]   sigma-z-permuted K, scaled by K_SCALE
// 16640   : W2T  bf16 [128][128]  sigma-permuted K,   scaled by K_SCALE
// 49408   : W3T  bf16 [64][128]   sigma-permuted K,   UNSCALED

__device__ __forceinline__ unsigned short f2bf(float f) {
    unsigned u = __float_as_uint(f);
    u += 0x7FFFu + ((u >> 16) & 1u);   // RNE
    return (unsigned short)(u >> 16);
}

// acc already holds 2*log2e*x: tanh(x) = 1 - 2/(2^acc + 1). Saturates cleanly.
__device__ __forceinline__ float tanh_scaled(float a) {
    float e;
    asm("v_exp_f32 %0, %1" : "=v"(e) : "v"(a));
    return fmaf(-2.0f, __builtin_amdgcn_rcpf(e + 1.0f), 1.0f);
}

__device__ __forceinline__ unsigned cvt_pk_bf16(float lo, float hi) {
    unsigned r;
    asm("v_cvt_pk_bf16_f32 %0, %1, %2" : "=v"(r) : "v"(lo), "v"(hi));
    return r;
}

// K-index bit permutation: [kt][q:2][j2:1][j:2] -> [kt][j2:1][q:2][j:2].
// Baking sigma into the consumer weight's K order makes the producer MFMA's
// C-layout output (lane-local, col = lane&15 = own batch row) coincide
// EXACTLY with the consumer MFMA's B-fragment register layout.
__device__ __forceinline__ int sigma(int m) {
    return (m & 96) | ((m & 4) << 2) | ((m >> 1) & 12) | (m & 3);
}

// ---------- kernel 1: per-block td maxes (blocks 0..63) + prep (64..191) ----
__global__ void k_pre(const float* __restrict__ td, const float* __restrict__ W1,
                      const float* __restrict__ W2, const float* __restrict__ W3,
                      float* __restrict__ ws) {
    if (blockIdx.x < 64) {
        __shared__ float red[4];
        float m = 0.0f;
        for (int i = blockIdx.x * 256 + threadIdx.x; i < B_N; i += 64 * 256)
            m = fmaxf(m, fabsf(td[i]));
#pragma unroll
        for (int o = 32; o; o >>= 1) m = fmaxf(m, __shfl_down(m, o));
        if ((threadIdx.x & 63) == 0) red[threadIdx.x >> 6] = m;
        __syncthreads();
        if (threadIdx.x == 0)
            ws[blockIdx.x] = fmaxf(fmaxf(red[0], red[1]), fmaxf(red[2], red[3]));
    } else {
        // 128 blocks * 256 threads = 32768 = exactly one bf16 element each
        int i = (blockIdx.x - 64) * 256 + threadIdx.x;
        unsigned short* wsb = (unsigned short*)((char*)ws + 256);
        float v;
        if (i < 8192) {                    // WzT[n][m] = K*W1[sigma(m)][n]
            int n = i >> 6, m = i & 63;
            v = W1[sigma(m) * 128 + n] * K_SCALE;
        } else if (i < 24576) {            // W2T[n][m] = K*W2[sigma(m)][n]
            int o = i - 8192;
            int n = o >> 7, m = o & 127;
            v = W2[sigma(m) * 128 + n] * K_SCALE;
        } else {                           // W3T[n][m] = W3[sigma(m)][n] (unscaled)
            int o = i - 24576;
            int n = o >> 7, m = o & 127;
            v = W3[sigma(m) * 64 + n];
        }
        wsb[i] = f2bf(v);
    }
}

// ---------- kernel 2: the ODE solver ----------
// 1 wave/SIMD (full 512-reg file per wave): ALL weights live in registers,
// the step loop has ZERO memory operations (no LDS, no global, no barriers).
// block = 256 = 4 waves (one per SIMD); grid = 256 = 1 block/CU;
// each wave runs 4 sequential 64-row tiles (prologue paid once).
// Step body is the R2/R10-verified dataflow, byte-identical.
__launch_bounds__(256, 1)
__global__ void k_main(const float* __restrict__ z_in, const float* __restrict__ td,
                       const float* __restrict__ W1, const float* __restrict__ b1,
                       const float* __restrict__ b2, const float* __restrict__ b3,
                       const void* __restrict__ ws, float* __restrict__ out) {
    const float* wsf = (const float*)ws;
    const unsigned short* wzg = (const unsigned short*)((const char*)ws + 256);
    const unsigned short* w2g = wzg + 8192;
    const unsigned short* w3g = wzg + 24576;

    const int tid = threadIdx.x;
    const int wave = tid >> 6;
    const int lane = tid & 63;
    const int q = lane >> 4;
    const int m15 = lane & 15;

    // ---- hoist ALL loop-invariant weights into registers ----
    bf16x8 wzf[8][2];   //  64 regs: Wz A-fragments (scaled)
    bf16x8 w2f[8][4];   // 128 regs: W2 A-fragments (scaled)
    bf16x8 w3f[4][4];   //  64 regs: W3 A-fragments (unscaled)
    bf16x8 augf[8];     //  32 regs: aug A-frag {pack(K*Wt, K*b1),0,0,0} on q==0
#pragma unroll
    for (int n0 = 0; n0 < 8; ++n0)
#pragma unroll
        for (int kt = 0; kt < 2; ++kt)
            wzf[n0][kt] = __builtin_bit_cast(
                bf16x8, *(const ushort8*)&wzg[(n0 * 16 + m15) * 64 + kt * 32 + q * 8]);
#pragma unroll
    for (int n0 = 0; n0 < 8; ++n0)
#pragma unroll
        for (int kt = 0; kt < 4; ++kt)
            w2f[n0][kt] = __builtin_bit_cast(
                bf16x8, *(const ushort8*)&w2g[(n0 * 16 + m15) * 128 + kt * 32 + q * 8]);
#pragma unroll
    for (int n0 = 0; n0 < 4; ++n0)
#pragma unroll
        for (int kt = 0; kt < 4; ++kt)
            w3f[n0][kt] = __builtin_bit_cast(
                bf16x8, *(const ushort8*)&w3g[(n0 * 16 + m15) * 128 + kt * 32 + q * 8]);
#pragma unroll
    for (int n0 = 0; n0 < 8; ++n0) {
        const int n = n0 * 16 + m15;
        float wt = W1[64 * 128 + n] * K_SCALE;   // Wt row of W1, scaled
        float bb = b1[n] * K_SCALE;
        unsigned w = (unsigned)f2bf(wt) | ((unsigned)f2bf(bb) << 16);
        w = (q == 0) ? w : 0u;                   // only k-slots 64,65 are live
        augf[n0] = __builtin_bit_cast(bf16x8, (uint32x4){w, 0u, 0u, 0u});
    }

    // b2 (scaled) rides in as the C-init of the first L2 MFMA
    f32x4 b2c[8];
#pragma unroll
    for (int n0 = 0; n0 < 8; ++n0) {
        f32x4 v = *(const f32x4*)&b2[n0 * 16 + q * 4];
#pragma unroll
        for (int r = 0; r < 4; ++r) v[r] *= K_SCALE;
        b2c[n0] = v;
    }

    // reduce the 64 per-block partial maxima (uniform, once per block;
    // fmax of non-negative floats == k_pre's previous atomicMax-on-bits)
    float maxab = 0.0f;
    for (int i = 0; i < 16; ++i) {
        f32x4 v = *(const f32x4*)&wsf[i * 4];
        maxab = fmaxf(maxab, fmaxf(fmaxf(v[0], v[1]), fmaxf(v[2], v[3])));
    }
    const int steps = (int)ceil((double)maxab / 0.1);   // matches np.ceil(float64)

    for (int tile = 0; tile < 4; ++tile) {
        const int row = blockIdx.x * 256 + tile * 64 + wave * 16 + m15;

        // zr[kt*8+hi*4+r] = z[row][kt*32 + hi*16 + q*4 + r]  (sigma_z baked in Wz)
        float zr[16];
#pragma unroll
        for (int kt = 0; kt < 2; ++kt)
#pragma unroll
            for (int hi = 0; hi < 2; ++hi) {
                f32x4 v = *(const f32x4*)(z_in + (size_t)row * 64 + kt * 32 + hi * 16 + q * 4);
#pragma unroll
                for (int r = 0; r < 4; ++r) zr[kt * 8 + hi * 4 + r] = v[r];
            }
        const float tdr = td[row];
        const float dtr = (steps > 0) ? (tdr / (float)steps) : 0.0f;

        for (int s = 0; s < steps; ++s) {
            const float t = (float)s * 0.1f;

            // ---- z -> bf16 B-fragments (8 cvt_pk) + t-augmentation word ----
            unsigned za[8];
#pragma unroll
            for (int i = 0; i < 8; ++i) za[i] = cvt_pk_bf16(zr[2 * i], zr[2 * i + 1]);
            unsigned tw = cvt_pk_bf16(t, 1.0f);
            tw = (q == 0) ? tw : 0u;
            bf16x8 zA0 = __builtin_bit_cast(bf16x8, (uint32x4){za[0], za[1], za[2], za[3]});
            bf16x8 zA1 = __builtin_bit_cast(bf16x8, (uint32x4){za[4], za[5], za[6], za[7]});
            bf16x8 zA2 = __builtin_bit_cast(bf16x8, (uint32x4){tw, 0u, 0u, 0u});

            // ---- layer 1: pre1 = K*(z@Wz + t*Wt + b1); h1 = tanh_scaled ----
            unsigned hv[16];
#pragma unroll
            for (int n0 = 0; n0 < 8; ++n0) {
                f32x4 acc = {0.f, 0.f, 0.f, 0.f};
                acc = __builtin_amdgcn_mfma_f32_16x16x32_bf16(wzf[n0][0], zA0, acc, 0, 0, 0);
                acc = __builtin_amdgcn_mfma_f32_16x16x32_bf16(wzf[n0][1], zA1, acc, 0, 0, 0);
                acc = __builtin_amdgcn_mfma_f32_16x16x32_bf16(augf[n0],   zA2, acc, 0, 0, 0);
                hv[n0 * 2 + 0] = cvt_pk_bf16(tanh_scaled(acc[0]), tanh_scaled(acc[1]));
                hv[n0 * 2 + 1] = cvt_pk_bf16(tanh_scaled(acc[2]), tanh_scaled(acc[3]));
            }

            // ---- layer 2: pre2 = K*(h1@W2 + b2) via scaled W2 + b2c C-init ----
            unsigned gv[16];
#pragma unroll
            for (int n0 = 0; n0 < 8; ++n0) {
                f32x4 acc = b2c[n0];
#pragma unroll
                for (int kt = 0; kt < 4; ++kt) {
                    bf16x8 hf = __builtin_bit_cast(
                        bf16x8, (uint32x4){hv[4 * kt], hv[4 * kt + 1],
                                           hv[4 * kt + 2], hv[4 * kt + 3]});
                    acc = __builtin_amdgcn_mfma_f32_16x16x32_bf16(w2f[n0][kt], hf, acc, 0, 0, 0);
                }
                gv[n0 * 2 + 0] = cvt_pk_bf16(tanh_scaled(acc[0]), tanh_scaled(acc[1]));
                gv[n0 * 2 + 1] = cvt_pk_bf16(tanh_scaled(acc[2]), tanh_scaled(acc[3]));
            }

            // ---- layer 3: dz = h2@W3 (unscaled); acc lands on zr[n0*4+r] ----
#pragma unroll
            for (int n0 = 0; n0 < 4; ++n0) {
                f32x4 acc = {0.f, 0.f, 0.f, 0.f};
#pragma unroll
                for (int kt = 0; kt < 4; ++kt) {
                    bf16x8 gf = __builtin_bit_cast(
                        bf16x8, (uint32x4){gv[4 * kt], gv[4 * kt + 1],
                                           gv[4 * kt + 2], gv[4 * kt + 3]});
                    acc = __builtin_amdgcn_mfma_f32_16x16x32_bf16(w3f[n0][kt], gf, acc, 0, 0, 0);
                }
#pragma unroll
                for (int r = 0; r < 4; ++r)
                    zr[n0 * 4 + r] = fmaf(acc[r], dtr, zr[n0 * 4 + r]);
            }
        }

        // b3 fold: sum_s dtr*b3 == td*b3 (exact linear fold, dz kept f32)
        const float tb3 = (steps > 0) ? tdr : 0.0f;
#pragma unroll
        for (int n0 = 0; n0 < 4; ++n0) {
            f32x4 bb = *(const f32x4*)&b3[n0 * 16 + q * 4];
#pragma unroll
            for (int r = 0; r < 4; ++r)
                zr[n0 * 4 + r] = fmaf(tb3, bb[r], zr[n0 * 4 + r]);
        }

        // store final z
#pragma unroll
        for (int kt = 0; kt < 2; ++kt)
#pragma unroll
            for (int hi = 0; hi < 2; ++hi) {
                f32x4 v;
#pragma unroll
                for (int r = 0; r < 4; ++r) v[r] = zr[kt * 8 + hi * 4 + r];
                *(f32x4*)(out + (size_t)row * 64 + kt * 32 + hi * 16 + q * 4) = v;
            }
    }
}

extern "C" void kernel_launch(void* const* d_in, const int* in_sizes, int n_in,
                              void* d_out, int out_size, void* d_ws, size_t ws_size,
                              hipStream_t stream) {
    const float* z  = (const float*)d_in[0];
    const float* td = (const float*)d_in[1];
    const float* W1 = (const float*)d_in[2];
    const float* b1 = (const float*)d_in[3];
    const float* W2 = (const float*)d_in[4];
    const float* b2 = (const float*)d_in[5];
    const float* W3 = (const float*)d_in[6];
    const float* b3 = (const float*)d_in[7];
    float* out = (float*)d_out;
    (void)in_sizes; (void)n_in; (void)out_size; (void)ws_size;

    k_pre<<<192, 256, 0, stream>>>(td, W1, W2, W3, (float*)d_ws);
    k_main<<<256, 256, 0, stream>>>(z, td, W1, b1, b2, b3, d_ws, out);
}